// Round 4
// baseline (121.652 us; speedup 1.0000x reference)
//
#include <hip/hip_runtime.h>
#include <math.h>

// DeepHit loss, MI355X. R=2 risks, B=8192, T=64 bins.
// Ints/bools all delivered as int32 by the harness (verified R2: absmax 0).
//
// Pipeline: memset(768B) -> prep1 (1-block LDS histogram + prefix) ->
// prep2 (counting-sort positions) -> k_cum (wave-per-(sample,risk) shuffle
// scan, event-compacted transposed store + likelihood) -> k_rank
// (bin-blocked: lanes=events in registers, censored loop with uniform
// scalar 'a') -> k_final.
//
// R3 post-mortem: k_cum grid expression evaluated to 64 blocks instead of
// 4096 -> only 1/64 of samples processed (absmax 65536, passed only via
// poison-luck). Fixed to an explicit 4096.

namespace {
constexpr int R  = 2;
constexpr int Bn = 8192;
constexpr int Tn = 64;
constexpr float INV_SIGMA = 10.0f;   // 1/0.1
constexpr float EPS       = 1e-8f;
}

// ws layout (bytes):
// 0     float llsumArr[2][32]
// 256   int   cntArr[2][32]
// 512   float rlsumArr[2][32]
// 768   int limE[64]     (inclusive prefix of event bins)
// 1024  int cbase[64]    (exclusive prefix of censored bins)
// 1280  int ncens[64]
// 1536  int scatEw[64]   (working counters, init = event excl prefix)
// 1792  int scatCw[64]   (working counters, init = cbase)
// 2048  int pos[8192]
// 34816 float aCens[2][8192]
// 100352 float cumTs[2][64][8192]  (event-compacted transposed cumsum rows)

__global__ void prep1(const int* __restrict__ tb, const int* __restrict__ ev,
                      int* limE, int* cbase, int* ncens, int* scatEw, int* scatCw) {
    __shared__ int hE[Tn], hC[Tn];
    int tid = threadIdx.x;
    if (tid < Tn) { hE[tid] = 0; hC[tid] = 0; }
    __syncthreads();
    for (int j = tid; j < Bn; j += 1024) {
        int t = tb[j];
        if (ev[j]) atomicAdd(&hE[t], 1);
        else       atomicAdd(&hC[t], 1);
    }
    __syncthreads();
    if (tid == 0) {
        int ae = 0, ac = 0;
        for (int t = 0; t < Tn; ++t) {
            scatEw[t] = ae; ae += hE[t]; limE[t] = ae;
            cbase[t] = ac; scatCw[t] = ac; ncens[t] = hC[t]; ac += hC[t];
        }
    }
}

__global__ void prep2(const int* __restrict__ tb, const int* __restrict__ ev,
                      int* scatEw, int* scatCw, int* pos) {
    int j = blockIdx.x * 256 + threadIdx.x;
    int t = tb[j];
    pos[j] = ev[j] ? atomicAdd(&scatEw[t], 1) : atomicAdd(&scatCw[t], 1);
}

__global__ void k_cum(const float* __restrict__ risk, const int* __restrict__ tb,
                      const int* __restrict__ rind, const int* __restrict__ ev,
                      const int* __restrict__ pos,
                      float* __restrict__ cumTs, float* __restrict__ aCens,
                      float* llsumArr, int* cntArr) {
    int w    = threadIdx.x >> 6;
    int lane = threadIdx.x & 63;
    int idx  = blockIdx.x * 4 + w;      // 0..16383 == r*Bn + i
    int i = idx & (Bn - 1);
    int r = idx >> 13;

    float v = risk[(size_t)idx * Tn + lane];   // coalesced 256B per wave
    float c = v;
#pragma unroll
    for (int o = 1; o < 64; o <<= 1) {         // inclusive wave prefix-scan
        float u = __shfl_up(c, o, 64);
        if (lane >= o) c += u;
    }

    int  ti = tb[i];
    bool e  = ev[i] != 0;
    int  po = pos[i];

    if (e)  // lane 'lane' stores cum at t=lane into transposed compact row
        cumTs[((size_t)(r * Tn + lane)) * Bn + po] = c;

    float a = __shfl(c, ti, 64);
    float p = __shfl(v, ti, 64);
    if (lane == 0) {
        if (e) {
            if (rind[i * R + r]) {
                int slot = r * 32 + (blockIdx.x & 31);
                atomicAdd(&llsumArr[slot], logf(p + EPS));
                atomicAdd(&cntArr[slot], 1);
            }
        } else {
            aCens[r * Bn + po] = a;   // po is global censored-sorted position
        }
    }
}

__global__ void k_rank(const float* __restrict__ cumTs, const float* __restrict__ aCens,
                       const int* __restrict__ limE, const int* __restrict__ cbase,
                       const int* __restrict__ ncens, float* rlsumArr) {
    int t = blockIdx.z, r = blockIdx.y, ec = blockIdx.x;
    int ne = limE[t];
    if (ec * 1024 >= ne) return;
    int nc = ncens[t];
    if (nc == 0) return;

    int j0 = ec * 1024 + threadIdx.x * 4;
    const float* rowp = cumTs + ((size_t)(r * Tn + t)) * Bn;
    float4 c4 = *reinterpret_cast<const float4*>(rowp + j0);
    // pre-scale by 1/sigma; out-of-range events -> +inf => sigmoid term 0
    float c0 = (j0 + 0 < ne) ? c4.x * INV_SIGMA : INFINITY;
    float c1 = (j0 + 1 < ne) ? c4.y * INV_SIGMA : INFINITY;
    float c2 = (j0 + 2 < ne) ? c4.z * INV_SIGMA : INFINITY;
    float c3 = (j0 + 3 < ne) ? c4.w * INV_SIGMA : INFINITY;

    const float* aC = aCens + r * Bn + cbase[t];
    float s0 = 0.f, s1 = 0.f, s2 = 0.f, s3 = 0.f;
#pragma unroll 4
    for (int ii = 0; ii < nc; ++ii) {
        float a10 = aC[ii] * INV_SIGMA;        // wave-uniform load
        s0 += __builtin_amdgcn_rcpf(1.f + __expf(c0 - a10));
        s1 += __builtin_amdgcn_rcpf(1.f + __expf(c1 - a10));
        s2 += __builtin_amdgcn_rcpf(1.f + __expf(c2 - a10));
        s3 += __builtin_amdgcn_rcpf(1.f + __expf(c3 - a10));
    }
    float s = (s0 + s1) + (s2 + s3);
#pragma unroll
    for (int o = 32; o > 0; o >>= 1) s += __shfl_down(s, o, 64);
    if ((threadIdx.x & 63) == 0) {
        int slot = r * 32 + ((blockIdx.z * 8 + blockIdx.x) & 31);
        atomicAdd(&rlsumArr[slot], s);
    }
}

__global__ void k_final(const float* llsumArr, const int* cntArr,
                        const float* rlsumArr, float* out) {
    int lane = threadIdx.x;       // 64 threads; layout [r][32] == [lane]
    float lg = llsumArr[lane];
    float rl = rlsumArr[lane];
    int   cn = cntArr[lane];
#pragma unroll
    for (int o = 1; o <= 16; o <<= 1) {   // reduce within each 32-half
        lg += __shfl_xor(lg, o, 64);
        rl += __shfl_xor(rl, o, 64);
        cn += __shfl_xor(cn, o, 64);
    }
    float lg1 = __shfl(lg, 32, 64);
    float rl1 = __shfl(rl, 32, 64);
    int   cn1 = __shfl(cn, 32, 64);
    if (lane == 0) {
        float ll0 = (cn  > 0) ? (-lg  / (float)cn ) : 0.f;
        float ll1 = (cn1 > 0) ? (-lg1 / (float)cn1) : 0.f;
        out[0] = 0.5f * (ll0 + ll1) + 0.5f * (rl + rl1);
    }
}

extern "C" void kernel_launch(void* const* d_in, const int* in_sizes, int n_in,
                              void* d_out, int out_size, void* d_ws, size_t ws_size,
                              hipStream_t stream) {
    const float* risk = (const float*)d_in[0];
    const int* tb     = (const int*)d_in[1];
    const int* rind   = (const int*)d_in[2];
    const int* ev     = (const int*)d_in[3];

    char* ws = (char*)d_ws;
    float* llsumArr = (float*)(ws + 0);
    int*   cntArr   = (int*)(ws + 256);
    float* rlsumArr = (float*)(ws + 512);
    int*   limE     = (int*)(ws + 768);
    int*   cbase    = (int*)(ws + 1024);
    int*   ncens    = (int*)(ws + 1280);
    int*   scatEw   = (int*)(ws + 1536);
    int*   scatCw   = (int*)(ws + 1792);
    int*   pos      = (int*)(ws + 2048);
    float* aCens    = (float*)(ws + 34816);
    float* cumTs    = (float*)(ws + 100352);

    hipMemsetAsync(ws, 0, 768, stream);   // accumulator slots only

    prep1<<<1, 1024, 0, stream>>>(tb, ev, limE, cbase, ncens, scatEw, scatCw);
    prep2<<<Bn / 256, 256, 0, stream>>>(tb, ev, scatEw, scatCw, pos);
    k_cum<<<(Bn * R) / 4, 256, 0, stream>>>(risk, tb, rind, ev, pos,
                                            cumTs, aCens, llsumArr, cntArr);
    dim3 gr(8, R, Tn);
    k_rank<<<gr, 256, 0, stream>>>(cumTs, aCens, limE, cbase, ncens, rlsumArr);
    k_final<<<1, 64, 0, stream>>>(llsumArr, cntArr, rlsumArr, (float*)d_out);
}

// Round 5
// 116.810 us; speedup vs baseline: 1.0415x; 1.0415x over previous
//
#include <hip/hip_runtime.h>
#include <math.h>

// DeepHit loss, MI355X. R=2 risks, B=8192, T=64 bins.
// Ints/bools delivered as int32 (verified R2/R4: absmax 0).
//
// Pipeline (4 dispatches):
//   k_prep  : 1 block — LDS histogram, prefix, counting-sort (esort/csort),
//             zero accumulators.
//   k_cum   : grid (256,R). blocks 0..127 = event tiles (64 samples): wave
//             shuffle-scan -> LDS tile -> coalesced transposed store to
//             cumTs + likelihood terms. blocks 128..255 = censored tiles:
//             masked row-sum -> aCens (censored-sorted).
//   k_rank  : grid (8,R,64). lanes hold 4 events (dense prefix [0,limE[t]))
//             in registers; loop over bin-t censored with wave-uniform 'a'.
//   k_final : combine.
//
// R4 post-mortem: k_cum's per-sample column scatter (64 lines/wave) cost
// ~22 us; replaced with LDS-transposed coalesced stores.

namespace {
constexpr int R  = 2;
constexpr int Bn = 8192;
constexpr int Tn = 64;
constexpr float INV_SIGMA = 10.0f;   // 1/0.1
constexpr float EPS       = 1e-8f;
}

// ws layout (bytes):
// 0      float llsumArr[2][32]
// 256    int   cntArr[2][32]
// 512    float rlsumArr[2][32]
// 768    int limE[64]     (inclusive prefix of event bins)
// 1024   int cbase[64]    (exclusive prefix of censored bins)
// 1280   int ncens[64]
// 2048   int esort[8192]  (event-sorted-by-bin -> sample idx)
// 34816  int csort[8192]  (censored-sorted-by-bin -> sample idx)
// 67584  float aCens[2][8192]
// 133120 float cumTs[2][64][8192]

__global__ void k_prep(const int* __restrict__ tb, const int* __restrict__ ev,
                       int* limE, int* cbase, int* ncensG,
                       int* esort, int* csort, int* accZero) {
    __shared__ int hE[Tn], hC[Tn], wE[Tn], wC[Tn];
    int tid = threadIdx.x;
    if (tid < Tn) { hE[tid] = 0; hC[tid] = 0; }
    if (tid < 192) accZero[tid] = 0;          // llsumArr/cntArr/rlsumArr
    __syncthreads();
    for (int j = tid; j < Bn; j += 1024) {
        int t = tb[j];
        if (ev[j]) atomicAdd(&hE[t], 1);
        else       atomicAdd(&hC[t], 1);
    }
    __syncthreads();
    if (tid == 0) {
        int ae = 0, ac = 0;
        for (int t = 0; t < Tn; ++t) {
            wE[t] = ae; ae += hE[t]; limE[t] = ae;
            wC[t] = ac; cbase[t] = ac; ncensG[t] = hC[t]; ac += hC[t];
        }
    }
    __syncthreads();
    for (int j = tid; j < Bn; j += 1024) {
        int t = tb[j];
        if (ev[j]) { int p = atomicAdd(&wE[t], 1); esort[p] = j; }
        else       { int p = atomicAdd(&wC[t], 1); csort[p] = j; }
    }
}

__global__ void __launch_bounds__(256)
k_cum(const float* __restrict__ risk, const int* __restrict__ tb,
      const int* __restrict__ rind,
      const int* __restrict__ limE, const int* __restrict__ cbase,
      const int* __restrict__ ncens,
      const int* __restrict__ esort, const int* __restrict__ csort,
      float* __restrict__ cumTs, float* __restrict__ aCens,
      float* llsumArr, int* cntArr) {
    const int r    = blockIdx.y;
    const int lane = threadIdx.x & 63;
    const int w    = threadIdx.x >> 6;
    __shared__ float S[Tn][Tn + 1];
    __shared__ int idxS[Tn];

    if (blockIdx.x < 128) {
        // ---- event tile: 64 event-sorted samples ----
        int nE = limE[Tn - 1];
        int k0 = blockIdx.x * 64;
        if (k0 >= nE) return;
        int cnt = min(64, nE - k0);
        if (threadIdx.x < cnt) idxS[threadIdx.x] = esort[k0 + threadIdx.x];
        __syncthreads();
        for (int s = 0; s < 16; ++s) {
            int ls = w * 16 + s;
            if (ls < cnt) {
                int i = idxS[ls];
                float v = risk[((size_t)r * Bn + i) * Tn + lane];  // 256B/wave
                float c = v;
#pragma unroll
                for (int o = 1; o < 64; o <<= 1) {                 // inclusive scan
                    float u = __shfl_up(c, o, 64);
                    if (lane >= o) c += u;
                }
                S[lane][ls] = c;          // bank = (lane+ls)%32 -> 2-way, free
                int ti = tb[i];
                float p = __shfl(v, ti, 64);
                if (lane == 0 && rind[i * R + r]) {
                    int slot = r * 32 + ((k0 + ls) & 31);
                    atomicAdd(&llsumArr[slot], logf(p + EPS));
                    atomicAdd(&cntArr[slot], 1);
                }
            }
        }
        __syncthreads();
        // transposed write-out: lanes = consecutive event columns (coalesced)
        float* dst = cumTs + ((size_t)r * Tn) * Bn + k0;
        int col = threadIdx.x & 63;
        int tr0 = threadIdx.x >> 6;
        if (col < cnt) {
#pragma unroll
            for (int m = 0; m < 16; ++m) {
                int t = m * 4 + tr0;
                dst[(size_t)t * Bn + col] = S[t][col];
            }
        }
    } else {
        // ---- censored tile: 64 censored-sorted samples, masked row-sum ----
        int nC = cbase[Tn - 1] + ncens[Tn - 1];
        int k0 = (blockIdx.x - 128) * 64;
        if (k0 >= nC) return;
        int cnt = min(64, nC - k0);
        if (threadIdx.x < cnt) idxS[threadIdx.x] = csort[k0 + threadIdx.x];
        __syncthreads();
        for (int s = 0; s < 16; ++s) {
            int ls = w * 16 + s;
            if (ls < cnt) {
                int i  = idxS[ls];
                int ti = tb[i];
                float v = risk[((size_t)r * Bn + i) * Tn + lane];
                v = (lane <= ti) ? v : 0.f;
#pragma unroll
                for (int o = 32; o > 0; o >>= 1) v += __shfl_down(v, o, 64);
                if (lane == 0) aCens[r * Bn + k0 + ls] = v;
            }
        }
    }
}

__global__ void k_rank(const float* __restrict__ cumTs, const float* __restrict__ aCens,
                       const int* __restrict__ limE, const int* __restrict__ cbase,
                       const int* __restrict__ ncens, float* rlsumArr) {
    int t = blockIdx.z, r = blockIdx.y, ec = blockIdx.x;
    int ne = limE[t];
    if (ec * 1024 >= ne) return;
    int nc = ncens[t];
    if (nc == 0) return;

    int j0 = ec * 1024 + threadIdx.x * 4;
    const float* rowp = cumTs + ((size_t)(r * Tn + t)) * Bn;
    float4 c4 = *reinterpret_cast<const float4*>(rowp + j0);
    // pre-scale by 1/sigma; out-of-range events -> +inf => sigmoid term 0
    float c0 = (j0 + 0 < ne) ? c4.x * INV_SIGMA : INFINITY;
    float c1 = (j0 + 1 < ne) ? c4.y * INV_SIGMA : INFINITY;
    float c2 = (j0 + 2 < ne) ? c4.z * INV_SIGMA : INFINITY;
    float c3 = (j0 + 3 < ne) ? c4.w * INV_SIGMA : INFINITY;

    const float* aC = aCens + r * Bn + cbase[t];
    float s0 = 0.f, s1 = 0.f, s2 = 0.f, s3 = 0.f;
#pragma unroll 4
    for (int ii = 0; ii < nc; ++ii) {
        float a10 = aC[ii] * INV_SIGMA;        // wave-uniform load
        s0 += __builtin_amdgcn_rcpf(1.f + __expf(c0 - a10));
        s1 += __builtin_amdgcn_rcpf(1.f + __expf(c1 - a10));
        s2 += __builtin_amdgcn_rcpf(1.f + __expf(c2 - a10));
        s3 += __builtin_amdgcn_rcpf(1.f + __expf(c3 - a10));
    }
    float s = (s0 + s1) + (s2 + s3);
#pragma unroll
    for (int o = 32; o > 0; o >>= 1) s += __shfl_down(s, o, 64);
    if ((threadIdx.x & 63) == 0) {
        int slot = r * 32 + ((blockIdx.z * 8 + blockIdx.x) & 31);
        atomicAdd(&rlsumArr[slot], s);
    }
}

__global__ void k_final(const float* llsumArr, const int* cntArr,
                        const float* rlsumArr, float* out) {
    int lane = threadIdx.x;       // 64 threads; layout [r][32]
    float lg = llsumArr[lane];
    float rl = rlsumArr[lane];
    int   cn = cntArr[lane];
#pragma unroll
    for (int o = 1; o <= 16; o <<= 1) {
        lg += __shfl_xor(lg, o, 64);
        rl += __shfl_xor(rl, o, 64);
        cn += __shfl_xor(cn, o, 64);
    }
    float lg1 = __shfl(lg, 32, 64);
    float rl1 = __shfl(rl, 32, 64);
    int   cn1 = __shfl(cn, 32, 64);
    if (lane == 0) {
        float ll0 = (cn  > 0) ? (-lg  / (float)cn ) : 0.f;
        float ll1 = (cn1 > 0) ? (-lg1 / (float)cn1) : 0.f;
        out[0] = 0.5f * (ll0 + ll1) + 0.5f * (rl + rl1);
    }
}

extern "C" void kernel_launch(void* const* d_in, const int* in_sizes, int n_in,
                              void* d_out, int out_size, void* d_ws, size_t ws_size,
                              hipStream_t stream) {
    const float* risk = (const float*)d_in[0];
    const int* tb     = (const int*)d_in[1];
    const int* rind   = (const int*)d_in[2];
    const int* ev     = (const int*)d_in[3];

    char* ws = (char*)d_ws;
    float* llsumArr = (float*)(ws + 0);
    int*   cntArr   = (int*)(ws + 256);
    float* rlsumArr = (float*)(ws + 512);
    int*   limE     = (int*)(ws + 768);
    int*   cbase    = (int*)(ws + 1024);
    int*   ncens    = (int*)(ws + 1280);
    int*   esort    = (int*)(ws + 2048);
    int*   csort    = (int*)(ws + 34816);
    float* aCens    = (float*)(ws + 67584);
    float* cumTs    = (float*)(ws + 133120);

    k_prep<<<1, 1024, 0, stream>>>(tb, ev, limE, cbase, ncens, esort, csort,
                                   (int*)ws);
    dim3 gc(256, R);
    k_cum<<<gc, 256, 0, stream>>>(risk, tb, rind, limE, cbase, ncens,
                                  esort, csort, cumTs, aCens, llsumArr, cntArr);
    dim3 gr(8, R, Tn);
    k_rank<<<gr, 256, 0, stream>>>(cumTs, aCens, limE, cbase, ncens, rlsumArr);
    k_final<<<1, 64, 0, stream>>>(llsumArr, cntArr, rlsumArr, (float*)d_out);
}